// Round 11
// baseline (117.236 us; speedup 1.0000x reference)
//
#include <hip/hip_runtime.h>

#define N_TOTAL 16384
#define NODE_DIM 64
#define HIDDEN 128
#define NPG 2048
#define NGRAPH 8
#define NPART 128

typedef float v4f __attribute__((ext_vector_type(4)));

// Pass-1 combined count+sum in one u32: enc = (1<<26) + (q + 2^19),
// q = lrint(s1 * 2^13), |s1| < 64 so |q| < 2^19. Per-slice deg <= 63,
// so count field (v>>26) is exact and lo field < 2^26. One LDS atomic
// per edge carries both count and sum; order-independent.
#define C1      (1 << 19)
#define SC1     8192.0f            // 2^13
#define ISC1    (1.0f / 8192.0f)
#define SC2     16384.0f           // 2^14 (pass 2, pure i32 wraparound sum)
#define ISC2    (1.0f / 16384.0f)

// Per-wave int32/int64 layout detect (no cross-block dependency):
// int64 little-endian with values < 2^31 => every odd 32-bit word is 0.
__device__ __forceinline__ int detect_flag(const int* ei_words) {
    int lane = threadIdx.x & 63;
    int nz = 0;
    for (int i = lane; i < 256; i += 64)
        if (ei_words[2 * i + 1] != 0) nz = 1;
    return __any(nz) ? 1 : 0;    // 1 => int32 layout, 0 => int64 layout
}

// On-demand rowsum of x[row,:] (64 floats). x is 4 MB -> L2/L3 resident.
__device__ __forceinline__ float rowsum_x(const float* __restrict__ x, int row) {
    const float4* xr = (const float4*)(x + row * NODE_DIM);
    float4 a = xr[0];
    #pragma unroll
    for (int j = 1; j < 16; ++j) a += xr[j];
    return a.x + a.y + a.z + a.w;
}

// ---------------------------------------------------------------- kScat1
// Block b: for its edge slice — decode (16B loads), compute s1[src] on
// demand, count+sum into combined u32 LDS table, write dec[] (uint4),
// dump partials. kS1 is fused away.
__global__ __launch_bounds__(512) void kScat1(
    const void* __restrict__ ei_raw, int E, const float* __restrict__ x,
    unsigned* __restrict__ pcomb, unsigned* __restrict__ dec) {
    __shared__ unsigned acc[N_TOTAL];   // 64 KB
    int tid = threadIdx.x, b = blockIdx.x;
    int f = detect_flag((const int*)ei_raw);
    for (int i = tid; i < N_TOTAL; i += 512) acc[i] = 0u;
    __syncthreads();
    int epb = (((E + NPART - 1) / NPART) + 3) & ~3;   // 4-aligned slice
    int e0 = b * epb, e1 = min(E, e0 + epb);
    int count = e1 - e0;
    if (count > 0) {
        int groups = count >> 2;
        if (f) {
            const int* ep  = (const int*)ei_raw;
            const int* epd = ep + E;
            for (int g = tid; g < groups; g += 512) {
                int eb = e0 + g * 4;
                int4 s4 = *(const int4*)(ep + eb);
                int4 d4 = *(const int4*)(epd + eb);
                float v0 = rowsum_x(x, s4.x), v1 = rowsum_x(x, s4.y);
                float v2 = rowsum_x(x, s4.z), v3 = rowsum_x(x, s4.w);
                uint4 dw;
                dw.x = (unsigned)s4.x | ((unsigned)d4.x << 16);
                dw.y = (unsigned)s4.y | ((unsigned)d4.y << 16);
                dw.z = (unsigned)s4.z | ((unsigned)d4.z << 16);
                dw.w = (unsigned)s4.w | ((unsigned)d4.w << 16);
                *(uint4*)(dec + eb) = dw;
                atomicAdd(&acc[d4.x], (1u << 26) + (unsigned)((int)lrintf(v0 * SC1) + C1));
                atomicAdd(&acc[d4.y], (1u << 26) + (unsigned)((int)lrintf(v1 * SC1) + C1));
                atomicAdd(&acc[d4.z], (1u << 26) + (unsigned)((int)lrintf(v2 * SC1) + C1));
                atomicAdd(&acc[d4.w], (1u << 26) + (unsigned)((int)lrintf(v3 * SC1) + C1));
            }
            int rem0 = e0 + groups * 4;
            if (tid < e1 - rem0) {
                int e = rem0 + tid;
                int s = ep[e], d = epd[e];
                dec[e] = (unsigned)s | ((unsigned)d << 16);
                float v = rowsum_x(x, s);
                atomicAdd(&acc[d], (1u << 26) + (unsigned)((int)lrintf(v * SC1) + C1));
            }
        } else {
            const long long* ep  = (const long long*)ei_raw;
            const long long* epd = ep + E;
            for (int g = tid; g < groups; g += 512) {
                int eb = e0 + g * 4;
                longlong2 sa = *(const longlong2*)(ep + eb);
                longlong2 sb = *(const longlong2*)(ep + eb + 2);
                longlong2 da = *(const longlong2*)(epd + eb);
                longlong2 db = *(const longlong2*)(epd + eb + 2);
                int s0 = (int)sa.x, s1i = (int)sa.y, s2i = (int)sb.x, s3 = (int)sb.y;
                int d0 = (int)da.x, d1 = (int)da.y, d2 = (int)db.x, d3 = (int)db.y;
                float v0 = rowsum_x(x, s0), v1 = rowsum_x(x, s1i);
                float v2 = rowsum_x(x, s2i), v3 = rowsum_x(x, s3);
                uint4 dw;
                dw.x = (unsigned)s0  | ((unsigned)d0 << 16);
                dw.y = (unsigned)s1i | ((unsigned)d1 << 16);
                dw.z = (unsigned)s2i | ((unsigned)d2 << 16);
                dw.w = (unsigned)s3  | ((unsigned)d3 << 16);
                *(uint4*)(dec + eb) = dw;
                atomicAdd(&acc[d0], (1u << 26) + (unsigned)((int)lrintf(v0 * SC1) + C1));
                atomicAdd(&acc[d1], (1u << 26) + (unsigned)((int)lrintf(v1 * SC1) + C1));
                atomicAdd(&acc[d2], (1u << 26) + (unsigned)((int)lrintf(v2 * SC1) + C1));
                atomicAdd(&acc[d3], (1u << 26) + (unsigned)((int)lrintf(v3 * SC1) + C1));
            }
            int rem0 = e0 + groups * 4;
            if (tid < e1 - rem0) {
                int e = rem0 + tid;
                int s = (int)ep[e], d = (int)epd[e];
                dec[e] = (unsigned)s | ((unsigned)d << 16);
                float v = rowsum_x(x, s);
                atomicAdd(&acc[d], (1u << 26) + (unsigned)((int)lrintf(v * SC1) + C1));
            }
        }
    }
    __syncthreads();
    unsigned* outp = pcomb + (size_t)b * N_TOTAL;
    for (int i = tid; i < N_TOTAL; i += 512) outp[i] = acc[i];
}

// ---------------------------------------------------------------- kScat2
// Block b: i32 fixed-point sum of s2[src] over its slice of dec[] (uint4
// loads); wraparound-exact; dump partials.
__global__ __launch_bounds__(512) void kScat2(
    const unsigned* __restrict__ dec, int E, const float* __restrict__ s2,
    int* __restrict__ ps2) {
    __shared__ int acc[N_TOTAL];   // 64 KB
    int tid = threadIdx.x, b = blockIdx.x;
    for (int i = tid; i < N_TOTAL; i += 512) acc[i] = 0;
    __syncthreads();
    int epb = (((E + NPART - 1) / NPART) + 3) & ~3;
    int e0 = b * epb, e1 = min(E, e0 + epb);
    int count = e1 - e0;
    if (count > 0) {
        int groups = count >> 2;
        for (int g = tid; g < groups; g += 512) {
            int eb = e0 + g * 4;
            uint4 dw = *(const uint4*)(dec + eb);
            float v0 = s2[dw.x & 0xFFFFu], v1 = s2[dw.y & 0xFFFFu];
            float v2 = s2[dw.z & 0xFFFFu], v3 = s2[dw.w & 0xFFFFu];
            atomicAdd((unsigned*)&acc[dw.x >> 16], (unsigned)(int)lrintf(v0 * SC2));
            atomicAdd((unsigned*)&acc[dw.y >> 16], (unsigned)(int)lrintf(v1 * SC2));
            atomicAdd((unsigned*)&acc[dw.z >> 16], (unsigned)(int)lrintf(v2 * SC2));
            atomicAdd((unsigned*)&acc[dw.w >> 16], (unsigned)(int)lrintf(v3 * SC2));
        }
        int rem0 = e0 + groups * 4;
        if (tid < e1 - rem0) {
            unsigned d32 = dec[rem0 + tid];
            float v = s2[d32 & 0xFFFFu];
            atomicAdd((unsigned*)&acc[d32 >> 16], (unsigned)(int)lrintf(v * SC2));
        }
    }
    __syncthreads();
    int* outp = ps2 + (size_t)b * N_TOTAL;
    for (int i = tid; i < N_TOTAL; i += 512) outp[i] = acc[i];
}

// ---------------------------------------------------------------- K3
// 32 rows/block. Prologue: coalesced reduce of combined partials -> mean1,
// degf. Main: h1 = relu(mean1 + x@W1 + b1) [NT store]; s2 = rowsum(h1).
__global__ __launch_bounds__(256) void k3_layer1(
    const float* __restrict__ x, const float* __restrict__ W1,
    const float* __restrict__ b1, const unsigned* __restrict__ pcomb,
    float* __restrict__ h1, float* __restrict__ s2, float* __restrict__ degf) {
    __shared__ float W1s[NODE_DIM * HIDDEN];   // 32 KB
    __shared__ float xs[32 * NODE_DIM];        // 8 KB
    __shared__ float mean1s[32];
    __shared__ int redc[4][32], reds[4][32];
    int tid  = threadIdx.x;
    int base = blockIdx.x * 32;
    {   // coalesced: r = tid&31 (consecutive addresses across lanes), jg = tid>>5
        int r = tid & 31, jg = tid >> 5;      // jg 0..7
        int c = 0, sq = 0;
        #pragma unroll
        for (int k = 0; k < 16; ++k) {
            unsigned v = pcomb[(size_t)(jg * 16 + k) * N_TOTAL + base + r];
            int n_i = (int)(v >> 26);
            c  += n_i;
            sq += (int)(v & 0x03FFFFFFu) - n_i * C1;
        }
        c  += __shfl_xor(c, 32);
        sq += __shfl_xor(sq, 32);
        int w = tid >> 6, l = tid & 63;
        if (l < 32) { redc[w][l] = c; reds[w][l] = sq; }
    }
    {
        const float4* Wv = (const float4*)W1;
        float4* Wsv = (float4*)W1s;
        for (int i = tid; i < NODE_DIM * HIDDEN / 4; i += 256) Wsv[i] = Wv[i];
        const float4* xv = (const float4*)(x + base * NODE_DIM);
        float4* xsv = (float4*)xs;
        for (int i = tid; i < 32 * NODE_DIM / 4; i += 256) xsv[i] = xv[i];
    }
    __syncthreads();
    if (tid < 32) {
        int C = redc[0][tid] + redc[1][tid] + redc[2][tid] + redc[3][tid];
        int S = reds[0][tid] + reds[1][tid] + reds[2][tid] + reds[3][tid];
        mean1s[tid] = C > 0 ? ((float)S * ISC1) / (float)C : 0.f;
        degf[base + tid] = (float)C;
    }
    __syncthreads();
    int lane32 = tid & 31;
    int rg     = tid >> 5;            // 0..7
    int c4     = lane32 * 4;
    int r0     = rg * 4;
    float a[4][4];
    #pragma unroll
    for (int i = 0; i < 4; ++i)
        #pragma unroll
        for (int jj = 0; jj < 4; ++jj) a[i][jj] = 0.f;
    #pragma unroll
    for (int k = 0; k < NODE_DIM; ++k) {
        float4 w = *(const float4*)&W1s[k * HIDDEN + c4];
        #pragma unroll
        for (int i = 0; i < 4; ++i) {
            float xv = xs[(r0 + i) * NODE_DIM + k];
            a[i][0] = fmaf(xv, w.x, a[i][0]);
            a[i][1] = fmaf(xv, w.y, a[i][1]);
            a[i][2] = fmaf(xv, w.z, a[i][2]);
            a[i][3] = fmaf(xv, w.w, a[i][3]);
        }
    }
    float4 bb = *(const float4*)&b1[c4];
    #pragma unroll
    for (int i = 0; i < 4; ++i) {
        int row  = r0 + i;
        int grow = base + row;
        float mean = mean1s[row];
        v4f v;
        v.x = fmaxf(mean + a[i][0] + bb.x, 0.f);
        v.y = fmaxf(mean + a[i][1] + bb.y, 0.f);
        v.z = fmaxf(mean + a[i][2] + bb.z, 0.f);
        v.w = fmaxf(mean + a[i][3] + bb.w, 0.f);
        __builtin_nontemporal_store(v, (v4f*)&h1[grow * HIDDEN + c4]);
        float rs = v.x + v.y + v.z + v.w;
        for (int off = 16; off; off >>= 1) rs += __shfl_xor(rs, off);
        if (lane32 == 0) s2[grow] = rs;
    }
}

// ---------------------------------------------------------------- K6
// 32 rows/block. Prologue: coalesced reduce of s2 partials / degf -> mean2.
// Main: left/right = relu(mean2 + h1@W2 + b2) . wlin halves.
__global__ __launch_bounds__(256) void k6_layer2(
    const float* __restrict__ h1, const float* __restrict__ W2,
    const float* __restrict__ b2, const int* __restrict__ ps2,
    const float* __restrict__ degf, const float* __restrict__ wlin,
    float* __restrict__ left, float* __restrict__ right) {
    __shared__ float W2s[64 * HIDDEN];   // 32 KB chunk
    __shared__ float hs[32 * HIDDEN];    // 16 KB
    __shared__ float mean2s[32];
    __shared__ int reds[4][32];
    int tid  = threadIdx.x;
    int base = blockIdx.x * 32;
    {
        int r = tid & 31, jg = tid >> 5;
        int sq = 0;
        #pragma unroll
        for (int k = 0; k < 16; ++k)
            sq += ps2[(size_t)(jg * 16 + k) * N_TOTAL + base + r];
        sq += __shfl_xor(sq, 32);
        int w = tid >> 6, l = tid & 63;
        if (l < 32) reds[w][l] = sq;
    }
    {
        const float4* hv = (const float4*)(h1 + base * HIDDEN);
        float4* hsv = (float4*)hs;
        for (int i = tid; i < 32 * HIDDEN / 4; i += 256) hsv[i] = hv[i];
    }
    __syncthreads();
    if (tid < 32) {
        int S = reds[0][tid] + reds[1][tid] + reds[2][tid] + reds[3][tid];
        float d = degf[base + tid];
        mean2s[tid] = d > 0.f ? ((float)S * ISC2) / d : 0.f;
    }
    int lane32 = tid & 31;
    int rg     = tid >> 5;
    int c4     = lane32 * 4;
    int r0     = rg * 4;
    float a[4][4];
    #pragma unroll
    for (int i = 0; i < 4; ++i)
        #pragma unroll
        for (int jj = 0; jj < 4; ++jj) a[i][jj] = 0.f;
    for (int chunk = 0; chunk < 2; ++chunk) {
        __syncthreads();
        {
            const float4* Wv = (const float4*)(W2 + chunk * 64 * HIDDEN);
            float4* Wsv = (float4*)W2s;
            for (int i = tid; i < 64 * HIDDEN / 4; i += 256) Wsv[i] = Wv[i];
        }
        __syncthreads();
        int kb = chunk * 64;
        #pragma unroll 8
        for (int k = 0; k < 64; ++k) {
            float4 w = *(const float4*)&W2s[k * HIDDEN + c4];
            #pragma unroll
            for (int i = 0; i < 4; ++i) {
                float hv = hs[(r0 + i) * HIDDEN + kb + k];
                a[i][0] = fmaf(hv, w.x, a[i][0]);
                a[i][1] = fmaf(hv, w.y, a[i][1]);
                a[i][2] = fmaf(hv, w.z, a[i][2]);
                a[i][3] = fmaf(hv, w.w, a[i][3]);
            }
        }
    }
    float4 bb  = *(const float4*)&b2[c4];
    float4 wl  = *(const float4*)&wlin[c4];
    float4 wr  = *(const float4*)&wlin[HIDDEN + c4];
    #pragma unroll
    for (int i = 0; i < 4; ++i) {
        int row  = r0 + i;
        int grow = base + row;
        float ag = mean2s[row];
        float h0e = fmaxf(ag + a[i][0] + bb.x, 0.f);
        float h1e = fmaxf(ag + a[i][1] + bb.y, 0.f);
        float h2e = fmaxf(ag + a[i][2] + bb.z, 0.f);
        float h3e = fmaxf(ag + a[i][3] + bb.w, 0.f);
        float lp = h0e * wl.x + h1e * wl.y + h2e * wl.z + h3e * wl.w;
        float rp = h0e * wr.x + h1e * wr.y + h2e * wr.z + h3e * wr.w;
        for (int off = 16; off; off >>= 1) {
            lp += __shfl_xor(lp, off);
            rp += __shfl_xor(rp, off);
        }
        if (lane32 == 0) { left[grow] = lp; right[grow] = rp; }
    }
}

// ---------------------------------------------------------------- K7
// 16 rows per block; right row L1-resident; nontemporal v4f stores.
__global__ __launch_bounds__(256) void k7_scores(
    const float* __restrict__ left, const float* __restrict__ right,
    const float* __restrict__ blin, float* __restrict__ out) {
    int tid  = threadIdx.x;
    int base = blockIdx.x * 16;
    float bl = blin[0];
    const v4f* rv4 = (const v4f*)(right + ((base >> 11) << 11));
    #pragma unroll 4
    for (int rr = 0; rr < 16; ++rr) {
        int r = base + rr;
        float L = left[r] + bl;
        v4f* orow = (v4f*)out + ((size_t)r << 9);
        #pragma unroll
        for (int c = tid; c < 512; c += 256) {
            v4f rv = rv4[c];
            v4f o;
            o.x = 1.f / (1.f + __expf(-(L + rv.x)));
            o.y = 1.f / (1.f + __expf(-(L + rv.y)));
            o.z = 1.f / (1.f + __expf(-(L + rv.z)));
            o.w = 1.f / (1.f + __expf(-(L + rv.w)));
            __builtin_nontemporal_store(o, orow + c);
        }
    }
}

// ---------------------------------------------------------------- launch
extern "C" void kernel_launch(void* const* d_in, const int* in_sizes, int n_in,
                              void* d_out, int out_size, void* d_ws, size_t ws_size,
                              hipStream_t stream) {
    const float* x    = (const float*)d_in[0];
    const void*  ei   = d_in[1];
    const float* W1   = (const float*)d_in[2];
    const float* b1   = (const float*)d_in[3];
    const float* W2   = (const float*)d_in[4];
    const float* b2   = (const float*)d_in[5];
    const float* wlin = (const float*)d_in[6];
    const float* blin = (const float*)d_in[7];
    int E = in_sizes[1] / 2;

    float* ws    = (float*)d_ws;
    float* s2    = ws;                                     // N
    float* degf  = ws + 1 * N_TOTAL;
    float* left  = ws + 2 * N_TOTAL;
    float* right = ws + 3 * N_TOTAL;
    float* h1    = ws + 4 * N_TOTAL;                       // N * 128
    unsigned* dec = (unsigned*)(h1 + (size_t)HIDDEN * N_TOTAL);  // E u32
    float* out   = (float*)d_out;

    // Partials live in d_out's head (16 MB << 127 MB); fully consumed by
    // k3/k6 before k7 overwrites the whole buffer (stream order).
    unsigned* pcomb = (unsigned*)d_out;                    // NPART * N u32
    int*      ps2   = (int*)d_out + (size_t)NPART * N_TOTAL;

    kScat1<<<NPART, 512, 0, stream>>>(ei, E, x, pcomb, dec);
    k3_layer1<<<N_TOTAL / 32, 256, 0, stream>>>(x, W1, b1, pcomb, h1, s2, degf);
    kScat2<<<NPART, 512, 0, stream>>>(dec, E, s2, ps2);
    k6_layer2<<<N_TOTAL / 32, 256, 0, stream>>>(h1, W2, b2, ps2, degf, wlin, left, right);
    k7_scores<<<N_TOTAL / 16, 256, 0, stream>>>(left, right, blin, out);
}

// Round 12
// 84.049 us; speedup vs baseline: 1.3948x; 1.3948x over previous
//
#include <hip/hip_runtime.h>

#define N_TOTAL 16384
#define NODE_DIM 64
#define HIDDEN 128
#define NPG 2048
#define NGRAPH 8
#define NPART 128

typedef float v4f __attribute__((ext_vector_type(4)));

// Pass-1 combined count+sum in one u32: enc = (1<<26) + (q + 2^19),
// q = lrint(s1 * 2^13), |s1| < 64 so |q| < 2^19. Per-slice deg <= 63,
// so count field (v>>26) is exact and lo field < 2^26. One LDS atomic
// per edge carries both count and sum; order-independent.
#define C1      (1 << 19)
#define SC1     8192.0f            // 2^13
#define ISC1    (1.0f / 8192.0f)
#define SC2     16384.0f           // 2^14 (pass 2, pure i32 wraparound sum)
#define ISC2    (1.0f / 16384.0f)

// Per-wave int32/int64 layout detect (no cross-block dependency):
// int64 little-endian with values < 2^31 => every odd 32-bit word is 0.
__device__ __forceinline__ int detect_flag(const int* ei_words) {
    int lane = threadIdx.x & 63;
    int nz = 0;
    for (int i = lane; i < 256; i += 64)
        if (ei_words[2 * i + 1] != 0) nz = 1;
    return __any(nz) ? 1 : 0;    // 1 => int32 layout, 0 => int64 layout
}

// ---------------------------------------------------------------- kS1
// s1[r] = rowsum(x[r,:]). 16 rows/block, 16 lanes/row. Computed ONCE per
// node (4 MB traffic) — round-11's per-edge recompute was a 134 MB/32µs
// regression.
__global__ __launch_bounds__(256) void kS1(
    const float* __restrict__ x, float* __restrict__ s1) {
    int tid = threadIdx.x;
    int r   = blockIdx.x * 16 + (tid >> 4);
    int q   = tid & 15;
    float4 v = ((const float4*)x)[r * 16 + q];
    float sum = v.x + v.y + v.z + v.w;
    sum += __shfl_xor(sum, 1);
    sum += __shfl_xor(sum, 2);
    sum += __shfl_xor(sum, 4);
    sum += __shfl_xor(sum, 8);
    if (q == 0) s1[r] = sum;
}

// ---------------------------------------------------------------- kScat1
// Block b: decode its edge slice (16B loads), gather s1[src], count+sum
// into combined u32 LDS table, write dec[] (uint4), dump partials.
__global__ __launch_bounds__(512) void kScat1(
    const void* __restrict__ ei_raw, int E, const float* __restrict__ s1,
    unsigned* __restrict__ pcomb, unsigned* __restrict__ dec) {
    __shared__ unsigned acc[N_TOTAL];   // 64 KB
    int tid = threadIdx.x, b = blockIdx.x;
    int f = detect_flag((const int*)ei_raw);
    for (int i = tid; i < N_TOTAL; i += 512) acc[i] = 0u;
    __syncthreads();
    int epb = (((E + NPART - 1) / NPART) + 3) & ~3;   // 4-aligned slice
    int e0 = b * epb, e1 = min(E, e0 + epb);
    int count = e1 - e0;
    if (count > 0) {
        int groups = count >> 2;
        if (f) {
            const int* ep  = (const int*)ei_raw;
            const int* epd = ep + E;
            for (int g = tid; g < groups; g += 512) {
                int eb = e0 + g * 4;
                int4 s4 = *(const int4*)(ep + eb);
                int4 d4 = *(const int4*)(epd + eb);
                float v0 = s1[s4.x], v1 = s1[s4.y];
                float v2 = s1[s4.z], v3 = s1[s4.w];
                uint4 dw;
                dw.x = (unsigned)s4.x | ((unsigned)d4.x << 16);
                dw.y = (unsigned)s4.y | ((unsigned)d4.y << 16);
                dw.z = (unsigned)s4.z | ((unsigned)d4.z << 16);
                dw.w = (unsigned)s4.w | ((unsigned)d4.w << 16);
                *(uint4*)(dec + eb) = dw;
                atomicAdd(&acc[d4.x], (1u << 26) + (unsigned)((int)lrintf(v0 * SC1) + C1));
                atomicAdd(&acc[d4.y], (1u << 26) + (unsigned)((int)lrintf(v1 * SC1) + C1));
                atomicAdd(&acc[d4.z], (1u << 26) + (unsigned)((int)lrintf(v2 * SC1) + C1));
                atomicAdd(&acc[d4.w], (1u << 26) + (unsigned)((int)lrintf(v3 * SC1) + C1));
            }
            int rem0 = e0 + groups * 4;
            if (tid < e1 - rem0) {
                int e = rem0 + tid;
                int s = ep[e], d = epd[e];
                dec[e] = (unsigned)s | ((unsigned)d << 16);
                atomicAdd(&acc[d], (1u << 26) + (unsigned)((int)lrintf(s1[s] * SC1) + C1));
            }
        } else {
            const long long* ep  = (const long long*)ei_raw;
            const long long* epd = ep + E;
            for (int g = tid; g < groups; g += 512) {
                int eb = e0 + g * 4;
                longlong2 sa = *(const longlong2*)(ep + eb);
                longlong2 sb = *(const longlong2*)(ep + eb + 2);
                longlong2 da = *(const longlong2*)(epd + eb);
                longlong2 db = *(const longlong2*)(epd + eb + 2);
                int s0 = (int)sa.x, s1i = (int)sa.y, s2i = (int)sb.x, s3 = (int)sb.y;
                int d0 = (int)da.x, d1 = (int)da.y, d2 = (int)db.x, d3 = (int)db.y;
                float v0 = s1[s0], v1 = s1[s1i], v2 = s1[s2i], v3 = s1[s3];
                uint4 dw;
                dw.x = (unsigned)s0  | ((unsigned)d0 << 16);
                dw.y = (unsigned)s1i | ((unsigned)d1 << 16);
                dw.z = (unsigned)s2i | ((unsigned)d2 << 16);
                dw.w = (unsigned)s3  | ((unsigned)d3 << 16);
                *(uint4*)(dec + eb) = dw;
                atomicAdd(&acc[d0], (1u << 26) + (unsigned)((int)lrintf(v0 * SC1) + C1));
                atomicAdd(&acc[d1], (1u << 26) + (unsigned)((int)lrintf(v1 * SC1) + C1));
                atomicAdd(&acc[d2], (1u << 26) + (unsigned)((int)lrintf(v2 * SC1) + C1));
                atomicAdd(&acc[d3], (1u << 26) + (unsigned)((int)lrintf(v3 * SC1) + C1));
            }
            int rem0 = e0 + groups * 4;
            if (tid < e1 - rem0) {
                int e = rem0 + tid;
                int s = (int)ep[e], d = (int)epd[e];
                dec[e] = (unsigned)s | ((unsigned)d << 16);
                atomicAdd(&acc[d], (1u << 26) + (unsigned)((int)lrintf(s1[s] * SC1) + C1));
            }
        }
    }
    __syncthreads();
    unsigned* outp = pcomb + (size_t)b * N_TOTAL;
    for (int i = tid; i < N_TOTAL; i += 512) outp[i] = acc[i];
}

// ---------------------------------------------------------------- kScat2
// Block b: i32 fixed-point sum of s2[src] over its slice of dec[] (uint4
// loads); wraparound-exact; dump partials.
__global__ __launch_bounds__(512) void kScat2(
    const unsigned* __restrict__ dec, int E, const float* __restrict__ s2,
    int* __restrict__ ps2) {
    __shared__ int acc[N_TOTAL];   // 64 KB
    int tid = threadIdx.x, b = blockIdx.x;
    for (int i = tid; i < N_TOTAL; i += 512) acc[i] = 0;
    __syncthreads();
    int epb = (((E + NPART - 1) / NPART) + 3) & ~3;
    int e0 = b * epb, e1 = min(E, e0 + epb);
    int count = e1 - e0;
    if (count > 0) {
        int groups = count >> 2;
        for (int g = tid; g < groups; g += 512) {
            int eb = e0 + g * 4;
            uint4 dw = *(const uint4*)(dec + eb);
            float v0 = s2[dw.x & 0xFFFFu], v1 = s2[dw.y & 0xFFFFu];
            float v2 = s2[dw.z & 0xFFFFu], v3 = s2[dw.w & 0xFFFFu];
            atomicAdd((unsigned*)&acc[dw.x >> 16], (unsigned)(int)lrintf(v0 * SC2));
            atomicAdd((unsigned*)&acc[dw.y >> 16], (unsigned)(int)lrintf(v1 * SC2));
            atomicAdd((unsigned*)&acc[dw.z >> 16], (unsigned)(int)lrintf(v2 * SC2));
            atomicAdd((unsigned*)&acc[dw.w >> 16], (unsigned)(int)lrintf(v3 * SC2));
        }
        int rem0 = e0 + groups * 4;
        if (tid < e1 - rem0) {
            unsigned d32 = dec[rem0 + tid];
            float v = s2[d32 & 0xFFFFu];
            atomicAdd((unsigned*)&acc[d32 >> 16], (unsigned)(int)lrintf(v * SC2));
        }
    }
    __syncthreads();
    int* outp = ps2 + (size_t)b * N_TOTAL;
    for (int i = tid; i < N_TOTAL; i += 512) outp[i] = acc[i];
}

// ---------------------------------------------------------------- K3
// 32 rows/block. Prologue: coalesced reduce of combined partials -> mean1,
// degf. Main: h1 = relu(mean1 + x@W1 + b1) [NT store]; s2 = rowsum(h1).
__global__ __launch_bounds__(256) void k3_layer1(
    const float* __restrict__ x, const float* __restrict__ W1,
    const float* __restrict__ b1, const unsigned* __restrict__ pcomb,
    float* __restrict__ h1, float* __restrict__ s2, float* __restrict__ degf) {
    __shared__ float W1s[NODE_DIM * HIDDEN];   // 32 KB
    __shared__ float xs[32 * NODE_DIM];        // 8 KB
    __shared__ float mean1s[32];
    __shared__ int redc[4][32], reds[4][32];
    int tid  = threadIdx.x;
    int base = blockIdx.x * 32;
    {   // coalesced: r = tid&31 (consecutive addresses across lanes), jg = tid>>5
        int r = tid & 31, jg = tid >> 5;      // jg 0..7
        int c = 0, sq = 0;
        #pragma unroll
        for (int k = 0; k < 16; ++k) {
            unsigned v = pcomb[(size_t)(jg * 16 + k) * N_TOTAL + base + r];
            int n_i = (int)(v >> 26);
            c  += n_i;
            sq += (int)(v & 0x03FFFFFFu) - n_i * C1;
        }
        c  += __shfl_xor(c, 32);
        sq += __shfl_xor(sq, 32);
        int w = tid >> 6, l = tid & 63;
        if (l < 32) { redc[w][l] = c; reds[w][l] = sq; }
    }
    {
        const float4* Wv = (const float4*)W1;
        float4* Wsv = (float4*)W1s;
        for (int i = tid; i < NODE_DIM * HIDDEN / 4; i += 256) Wsv[i] = Wv[i];
        const float4* xv = (const float4*)(x + base * NODE_DIM);
        float4* xsv = (float4*)xs;
        for (int i = tid; i < 32 * NODE_DIM / 4; i += 256) xsv[i] = xv[i];
    }
    __syncthreads();
    if (tid < 32) {
        int C = redc[0][tid] + redc[1][tid] + redc[2][tid] + redc[3][tid];
        int S = reds[0][tid] + reds[1][tid] + reds[2][tid] + reds[3][tid];
        mean1s[tid] = C > 0 ? ((float)S * ISC1) / (float)C : 0.f;
        degf[base + tid] = (float)C;
    }
    __syncthreads();
    int lane32 = tid & 31;
    int rg     = tid >> 5;            // 0..7
    int c4     = lane32 * 4;
    int r0     = rg * 4;
    float a[4][4];
    #pragma unroll
    for (int i = 0; i < 4; ++i)
        #pragma unroll
        for (int jj = 0; jj < 4; ++jj) a[i][jj] = 0.f;
    #pragma unroll
    for (int k = 0; k < NODE_DIM; ++k) {
        float4 w = *(const float4*)&W1s[k * HIDDEN + c4];
        #pragma unroll
        for (int i = 0; i < 4; ++i) {
            float xv = xs[(r0 + i) * NODE_DIM + k];
            a[i][0] = fmaf(xv, w.x, a[i][0]);
            a[i][1] = fmaf(xv, w.y, a[i][1]);
            a[i][2] = fmaf(xv, w.z, a[i][2]);
            a[i][3] = fmaf(xv, w.w, a[i][3]);
        }
    }
    float4 bb = *(const float4*)&b1[c4];
    #pragma unroll
    for (int i = 0; i < 4; ++i) {
        int row  = r0 + i;
        int grow = base + row;
        float mean = mean1s[row];
        v4f v;
        v.x = fmaxf(mean + a[i][0] + bb.x, 0.f);
        v.y = fmaxf(mean + a[i][1] + bb.y, 0.f);
        v.z = fmaxf(mean + a[i][2] + bb.z, 0.f);
        v.w = fmaxf(mean + a[i][3] + bb.w, 0.f);
        __builtin_nontemporal_store(v, (v4f*)&h1[grow * HIDDEN + c4]);
        float rs = v.x + v.y + v.z + v.w;
        for (int off = 16; off; off >>= 1) rs += __shfl_xor(rs, off);
        if (lane32 == 0) s2[grow] = rs;
    }
}

// ---------------------------------------------------------------- K6
// 32 rows/block. Prologue: coalesced reduce of s2 partials / degf -> mean2.
// Main: left/right = relu(mean2 + h1@W2 + b2) . wlin halves.
__global__ __launch_bounds__(256) void k6_layer2(
    const float* __restrict__ h1, const float* __restrict__ W2,
    const float* __restrict__ b2, const int* __restrict__ ps2,
    const float* __restrict__ degf, const float* __restrict__ wlin,
    float* __restrict__ left, float* __restrict__ right) {
    __shared__ float W2s[64 * HIDDEN];   // 32 KB chunk
    __shared__ float hs[32 * HIDDEN];    // 16 KB
    __shared__ float mean2s[32];
    __shared__ int reds[4][32];
    int tid  = threadIdx.x;
    int base = blockIdx.x * 32;
    {
        int r = tid & 31, jg = tid >> 5;
        int sq = 0;
        #pragma unroll
        for (int k = 0; k < 16; ++k)
            sq += ps2[(size_t)(jg * 16 + k) * N_TOTAL + base + r];
        sq += __shfl_xor(sq, 32);
        int w = tid >> 6, l = tid & 63;
        if (l < 32) reds[w][l] = sq;
    }
    {
        const float4* hv = (const float4*)(h1 + base * HIDDEN);
        float4* hsv = (float4*)hs;
        for (int i = tid; i < 32 * HIDDEN / 4; i += 256) hsv[i] = hv[i];
    }
    __syncthreads();
    if (tid < 32) {
        int S = reds[0][tid] + reds[1][tid] + reds[2][tid] + reds[3][tid];
        float d = degf[base + tid];
        mean2s[tid] = d > 0.f ? ((float)S * ISC2) / d : 0.f;
    }
    int lane32 = tid & 31;
    int rg     = tid >> 5;
    int c4     = lane32 * 4;
    int r0     = rg * 4;
    float a[4][4];
    #pragma unroll
    for (int i = 0; i < 4; ++i)
        #pragma unroll
        for (int jj = 0; jj < 4; ++jj) a[i][jj] = 0.f;
    for (int chunk = 0; chunk < 2; ++chunk) {
        __syncthreads();
        {
            const float4* Wv = (const float4*)(W2 + chunk * 64 * HIDDEN);
            float4* Wsv = (float4*)W2s;
            for (int i = tid; i < 64 * HIDDEN / 4; i += 256) Wsv[i] = Wv[i];
        }
        __syncthreads();
        int kb = chunk * 64;
        #pragma unroll 8
        for (int k = 0; k < 64; ++k) {
            float4 w = *(const float4*)&W2s[k * HIDDEN + c4];
            #pragma unroll
            for (int i = 0; i < 4; ++i) {
                float hv = hs[(r0 + i) * HIDDEN + kb + k];
                a[i][0] = fmaf(hv, w.x, a[i][0]);
                a[i][1] = fmaf(hv, w.y, a[i][1]);
                a[i][2] = fmaf(hv, w.z, a[i][2]);
                a[i][3] = fmaf(hv, w.w, a[i][3]);
            }
        }
    }
    float4 bb  = *(const float4*)&b2[c4];
    float4 wl  = *(const float4*)&wlin[c4];
    float4 wr  = *(const float4*)&wlin[HIDDEN + c4];
    #pragma unroll
    for (int i = 0; i < 4; ++i) {
        int row  = r0 + i;
        int grow = base + row;
        float ag = mean2s[row];
        float h0e = fmaxf(ag + a[i][0] + bb.x, 0.f);
        float h1e = fmaxf(ag + a[i][1] + bb.y, 0.f);
        float h2e = fmaxf(ag + a[i][2] + bb.z, 0.f);
        float h3e = fmaxf(ag + a[i][3] + bb.w, 0.f);
        float lp = h0e * wl.x + h1e * wl.y + h2e * wl.z + h3e * wl.w;
        float rp = h0e * wr.x + h1e * wr.y + h2e * wr.z + h3e * wr.w;
        for (int off = 16; off; off >>= 1) {
            lp += __shfl_xor(lp, off);
            rp += __shfl_xor(rp, off);
        }
        if (lane32 == 0) { left[grow] = lp; right[grow] = rp; }
    }
}

// ---------------------------------------------------------------- K7
// 16 rows per block; right row L1-resident; nontemporal v4f stores.
__global__ __launch_bounds__(256) void k7_scores(
    const float* __restrict__ left, const float* __restrict__ right,
    const float* __restrict__ blin, float* __restrict__ out) {
    int tid  = threadIdx.x;
    int base = blockIdx.x * 16;
    float bl = blin[0];
    const v4f* rv4 = (const v4f*)(right + ((base >> 11) << 11));
    #pragma unroll 4
    for (int rr = 0; rr < 16; ++rr) {
        int r = base + rr;
        float L = left[r] + bl;
        v4f* orow = (v4f*)out + ((size_t)r << 9);
        #pragma unroll
        for (int c = tid; c < 512; c += 256) {
            v4f rv = rv4[c];
            v4f o;
            o.x = 1.f / (1.f + __expf(-(L + rv.x)));
            o.y = 1.f / (1.f + __expf(-(L + rv.y)));
            o.z = 1.f / (1.f + __expf(-(L + rv.z)));
            o.w = 1.f / (1.f + __expf(-(L + rv.w)));
            __builtin_nontemporal_store(o, orow + c);
        }
    }
}

// ---------------------------------------------------------------- launch
extern "C" void kernel_launch(void* const* d_in, const int* in_sizes, int n_in,
                              void* d_out, int out_size, void* d_ws, size_t ws_size,
                              hipStream_t stream) {
    const float* x    = (const float*)d_in[0];
    const void*  ei   = d_in[1];
    const float* W1   = (const float*)d_in[2];
    const float* b1   = (const float*)d_in[3];
    const float* W2   = (const float*)d_in[4];
    const float* b2   = (const float*)d_in[5];
    const float* wlin = (const float*)d_in[6];
    const float* blin = (const float*)d_in[7];
    int E = in_sizes[1] / 2;

    float* ws    = (float*)d_ws;
    float* s1    = ws;                                     // N
    float* s2    = ws + 1 * N_TOTAL;
    float* degf  = ws + 2 * N_TOTAL;
    float* left  = ws + 3 * N_TOTAL;
    float* right = ws + 4 * N_TOTAL;
    float* h1    = ws + 5 * N_TOTAL;                       // N * 128
    unsigned* dec = (unsigned*)(h1 + (size_t)HIDDEN * N_TOTAL);  // E u32
    float* out   = (float*)d_out;

    // Partials live in d_out's head (16 MB << 127 MB); fully consumed by
    // k3/k6 before k7 overwrites the whole buffer (stream order).
    unsigned* pcomb = (unsigned*)d_out;                    // NPART * N u32
    int*      ps2   = (int*)d_out + (size_t)NPART * N_TOTAL;

    kS1<<<N_TOTAL / 16, 256, 0, stream>>>(x, s1);
    kScat1<<<NPART, 512, 0, stream>>>(ei, E, s1, pcomb, dec);
    k3_layer1<<<N_TOTAL / 32, 256, 0, stream>>>(x, W1, b1, pcomb, h1, s2, degf);
    kScat2<<<NPART, 512, 0, stream>>>(dec, E, s2, ps2);
    k6_layer2<<<N_TOTAL / 32, 256, 0, stream>>>(h1, W2, b2, ps2, degf, wlin, left, right);
    k7_scores<<<N_TOTAL / 16, 256, 0, stream>>>(left, right, blin, out);
}

// Round 13
// 81.396 us; speedup vs baseline: 1.4403x; 1.0326x over previous
//
#include <hip/hip_runtime.h>

#define N_TOTAL 16384
#define NODE_DIM 64
#define HIDDEN 128
#define NPG 2048
#define NGRAPH 8
#define NPART 128

typedef float v4f __attribute__((ext_vector_type(4)));

// Pass-1 combined count+sum in one u32: enc = (1<<26) + (q + 2^19),
// q = lrint(s1 * 2^13), |s1| < 64 so |q| < 2^19. Per-slice deg <= 63,
// so count field (v>>26) is exact and lo field < 2^26. One LDS atomic
// per edge carries both count and sum; order-independent.
#define C1      (1 << 19)
#define SC1     8192.0f            // 2^13
#define ISC1    (1.0f / 8192.0f)
#define SC2     16384.0f           // 2^14 (pass 2, pure i32 wraparound sum)
#define ISC2    (1.0f / 16384.0f)

// Per-wave int32/int64 layout detect (no cross-block dependency):
// int64 little-endian with values < 2^31 => every odd 32-bit word is 0.
__device__ __forceinline__ int detect_flag(const int* ei_words) {
    int lane = threadIdx.x & 63;
    int nz = 0;
    for (int i = lane; i < 256; i += 64)
        if (ei_words[2 * i + 1] != 0) nz = 1;
    return __any(nz) ? 1 : 0;    // 1 => int32 layout, 0 => int64 layout
}

// ---------------------------------------------------------------- kS1
// s1[r] = rowsum(x[r,:]). 16 rows/block, 16 lanes/row. Computed ONCE per
// node (4 MB traffic) — per-edge recompute was a 134 MB/32µs regression.
__global__ __launch_bounds__(256) void kS1(
    const float* __restrict__ x, float* __restrict__ s1) {
    int tid = threadIdx.x;
    int r   = blockIdx.x * 16 + (tid >> 4);
    int q   = tid & 15;
    float4 v = ((const float4*)x)[r * 16 + q];
    float sum = v.x + v.y + v.z + v.w;
    sum += __shfl_xor(sum, 1);
    sum += __shfl_xor(sum, 2);
    sum += __shfl_xor(sum, 4);
    sum += __shfl_xor(sum, 8);
    if (q == 0) s1[r] = sum;
}

// ---------------------------------------------------------------- kScat1
// Block b: decode its edge slice (16B loads, 8 edges/thread/iter), gather
// s1[src], count+sum into combined u32 LDS table, write dec[], dump
// partials (uint4). With E=512K, NPART=128: exactly ONE iteration/thread.
__global__ __launch_bounds__(512) void kScat1(
    const void* __restrict__ ei_raw, int E, const float* __restrict__ s1,
    unsigned* __restrict__ pcomb, unsigned* __restrict__ dec) {
    __shared__ unsigned acc[N_TOTAL];   // 64 KB
    int tid = threadIdx.x, b = blockIdx.x;
    int f = detect_flag((const int*)ei_raw);
    {   // uint4 zero
        uint4* av = (uint4*)acc;
        uint4 z; z.x = z.y = z.z = z.w = 0u;
        for (int i = tid; i < N_TOTAL / 4; i += 512) av[i] = z;
    }
    __syncthreads();
    int epb = (((E + NPART - 1) / NPART) + 7) & ~7;   // 8-aligned slice
    int e0 = b * epb, e1 = min(E, e0 + epb);
    int count = e1 - e0;
    if (count > 0) {
        int groups = count >> 3;    // 8-edge groups
        if (f) {
            const int* ep  = (const int*)ei_raw;
            const int* epd = ep + E;
            for (int g = tid; g < groups; g += 512) {
                int eb = e0 + g * 8;
                int4 sa = *(const int4*)(ep + eb);
                int4 sb = *(const int4*)(ep + eb + 4);
                int4 da = *(const int4*)(epd + eb);
                int4 db = *(const int4*)(epd + eb + 4);
                float v0 = s1[sa.x], v1 = s1[sa.y], v2 = s1[sa.z], v3 = s1[sa.w];
                float v4 = s1[sb.x], v5 = s1[sb.y], v6 = s1[sb.z], v7 = s1[sb.w];
                uint4 w0, w1;
                w0.x = (unsigned)sa.x | ((unsigned)da.x << 16);
                w0.y = (unsigned)sa.y | ((unsigned)da.y << 16);
                w0.z = (unsigned)sa.z | ((unsigned)da.z << 16);
                w0.w = (unsigned)sa.w | ((unsigned)da.w << 16);
                w1.x = (unsigned)sb.x | ((unsigned)db.x << 16);
                w1.y = (unsigned)sb.y | ((unsigned)db.y << 16);
                w1.z = (unsigned)sb.z | ((unsigned)db.z << 16);
                w1.w = (unsigned)sb.w | ((unsigned)db.w << 16);
                *(uint4*)(dec + eb)     = w0;
                *(uint4*)(dec + eb + 4) = w1;
                atomicAdd(&acc[da.x], (1u << 26) + (unsigned)((int)lrintf(v0 * SC1) + C1));
                atomicAdd(&acc[da.y], (1u << 26) + (unsigned)((int)lrintf(v1 * SC1) + C1));
                atomicAdd(&acc[da.z], (1u << 26) + (unsigned)((int)lrintf(v2 * SC1) + C1));
                atomicAdd(&acc[da.w], (1u << 26) + (unsigned)((int)lrintf(v3 * SC1) + C1));
                atomicAdd(&acc[db.x], (1u << 26) + (unsigned)((int)lrintf(v4 * SC1) + C1));
                atomicAdd(&acc[db.y], (1u << 26) + (unsigned)((int)lrintf(v5 * SC1) + C1));
                atomicAdd(&acc[db.z], (1u << 26) + (unsigned)((int)lrintf(v6 * SC1) + C1));
                atomicAdd(&acc[db.w], (1u << 26) + (unsigned)((int)lrintf(v7 * SC1) + C1));
            }
            int rem0 = e0 + groups * 8;
            if (tid < e1 - rem0) {
                int e = rem0 + tid;
                int s = ep[e], d = epd[e];
                dec[e] = (unsigned)s | ((unsigned)d << 16);
                atomicAdd(&acc[d], (1u << 26) + (unsigned)((int)lrintf(s1[s] * SC1) + C1));
            }
        } else {
            const long long* ep  = (const long long*)ei_raw;
            const long long* epd = ep + E;
            for (int g = tid; g < groups; g += 512) {
                int eb = e0 + g * 8;
                longlong2 sa = *(const longlong2*)(ep + eb);
                longlong2 sb = *(const longlong2*)(ep + eb + 2);
                longlong2 sc = *(const longlong2*)(ep + eb + 4);
                longlong2 sd = *(const longlong2*)(ep + eb + 6);
                longlong2 da = *(const longlong2*)(epd + eb);
                longlong2 db = *(const longlong2*)(epd + eb + 2);
                longlong2 dc = *(const longlong2*)(epd + eb + 4);
                longlong2 dd = *(const longlong2*)(epd + eb + 6);
                int s0 = (int)sa.x, s1i = (int)sa.y, s2i = (int)sb.x, s3 = (int)sb.y;
                int s4 = (int)sc.x, s5 = (int)sc.y, s6 = (int)sd.x, s7 = (int)sd.y;
                int d0 = (int)da.x, d1 = (int)da.y, d2 = (int)db.x, d3 = (int)db.y;
                int d4 = (int)dc.x, d5 = (int)dc.y, d6 = (int)dd.x, d7 = (int)dd.y;
                float v0 = s1[s0], v1 = s1[s1i], v2 = s1[s2i], v3 = s1[s3];
                float v4 = s1[s4], v5 = s1[s5],  v6 = s1[s6],  v7 = s1[s7];
                uint4 w0, w1;
                w0.x = (unsigned)s0  | ((unsigned)d0 << 16);
                w0.y = (unsigned)s1i | ((unsigned)d1 << 16);
                w0.z = (unsigned)s2i | ((unsigned)d2 << 16);
                w0.w = (unsigned)s3  | ((unsigned)d3 << 16);
                w1.x = (unsigned)s4  | ((unsigned)d4 << 16);
                w1.y = (unsigned)s5  | ((unsigned)d5 << 16);
                w1.z = (unsigned)s6  | ((unsigned)d6 << 16);
                w1.w = (unsigned)s7  | ((unsigned)d7 << 16);
                *(uint4*)(dec + eb)     = w0;
                *(uint4*)(dec + eb + 4) = w1;
                atomicAdd(&acc[d0], (1u << 26) + (unsigned)((int)lrintf(v0 * SC1) + C1));
                atomicAdd(&acc[d1], (1u << 26) + (unsigned)((int)lrintf(v1 * SC1) + C1));
                atomicAdd(&acc[d2], (1u << 26) + (unsigned)((int)lrintf(v2 * SC1) + C1));
                atomicAdd(&acc[d3], (1u << 26) + (unsigned)((int)lrintf(v3 * SC1) + C1));
                atomicAdd(&acc[d4], (1u << 26) + (unsigned)((int)lrintf(v4 * SC1) + C1));
                atomicAdd(&acc[d5], (1u << 26) + (unsigned)((int)lrintf(v5 * SC1) + C1));
                atomicAdd(&acc[d6], (1u << 26) + (unsigned)((int)lrintf(v6 * SC1) + C1));
                atomicAdd(&acc[d7], (1u << 26) + (unsigned)((int)lrintf(v7 * SC1) + C1));
            }
            int rem0 = e0 + groups * 8;
            if (tid < e1 - rem0) {
                int e = rem0 + tid;
                int s = (int)ep[e], d = (int)epd[e];
                dec[e] = (unsigned)s | ((unsigned)d << 16);
                atomicAdd(&acc[d], (1u << 26) + (unsigned)((int)lrintf(s1[s] * SC1) + C1));
            }
        }
    }
    __syncthreads();
    {   // uint4 dump
        const uint4* av = (const uint4*)acc;
        uint4* outp = (uint4*)(pcomb + (size_t)b * N_TOTAL);
        for (int i = tid; i < N_TOTAL / 4; i += 512) outp[i] = av[i];
    }
}

// ---------------------------------------------------------------- kScat2
// Block b: i32 fixed-point sum of s2[src] over its slice of dec[] (uint4
// loads, 8 edges/thread/iter); wraparound-exact; uint4 dump.
__global__ __launch_bounds__(512) void kScat2(
    const unsigned* __restrict__ dec, int E, const float* __restrict__ s2,
    int* __restrict__ ps2) {
    __shared__ int acc[N_TOTAL];   // 64 KB
    int tid = threadIdx.x, b = blockIdx.x;
    {
        uint4* av = (uint4*)acc;
        uint4 z; z.x = z.y = z.z = z.w = 0u;
        for (int i = tid; i < N_TOTAL / 4; i += 512) av[i] = z;
    }
    __syncthreads();
    int epb = (((E + NPART - 1) / NPART) + 7) & ~7;
    int e0 = b * epb, e1 = min(E, e0 + epb);
    int count = e1 - e0;
    if (count > 0) {
        int groups = count >> 3;
        for (int g = tid; g < groups; g += 512) {
            int eb = e0 + g * 8;
            uint4 w0 = *(const uint4*)(dec + eb);
            uint4 w1 = *(const uint4*)(dec + eb + 4);
            float v0 = s2[w0.x & 0xFFFFu], v1 = s2[w0.y & 0xFFFFu];
            float v2 = s2[w0.z & 0xFFFFu], v3 = s2[w0.w & 0xFFFFu];
            float v4 = s2[w1.x & 0xFFFFu], v5 = s2[w1.y & 0xFFFFu];
            float v6 = s2[w1.z & 0xFFFFu], v7 = s2[w1.w & 0xFFFFu];
            atomicAdd((unsigned*)&acc[w0.x >> 16], (unsigned)(int)lrintf(v0 * SC2));
            atomicAdd((unsigned*)&acc[w0.y >> 16], (unsigned)(int)lrintf(v1 * SC2));
            atomicAdd((unsigned*)&acc[w0.z >> 16], (unsigned)(int)lrintf(v2 * SC2));
            atomicAdd((unsigned*)&acc[w0.w >> 16], (unsigned)(int)lrintf(v3 * SC2));
            atomicAdd((unsigned*)&acc[w1.x >> 16], (unsigned)(int)lrintf(v4 * SC2));
            atomicAdd((unsigned*)&acc[w1.y >> 16], (unsigned)(int)lrintf(v5 * SC2));
            atomicAdd((unsigned*)&acc[w1.z >> 16], (unsigned)(int)lrintf(v6 * SC2));
            atomicAdd((unsigned*)&acc[w1.w >> 16], (unsigned)(int)lrintf(v7 * SC2));
        }
        int rem0 = e0 + groups * 8;
        if (tid < e1 - rem0) {
            unsigned d32 = dec[rem0 + tid];
            float v = s2[d32 & 0xFFFFu];
            atomicAdd((unsigned*)&acc[d32 >> 16], (unsigned)(int)lrintf(v * SC2));
        }
    }
    __syncthreads();
    {
        const uint4* av = (const uint4*)acc;
        uint4* outp = (uint4*)(ps2 + (size_t)b * N_TOTAL);
        for (int i = tid; i < N_TOTAL / 4; i += 512) outp[i] = av[i];
    }
}

// ---------------------------------------------------------------- K3
// 32 rows/block. Prologue: coalesced reduce of combined partials -> mean1,
// degf. Main: h1 = relu(mean1 + x@W1 + b1) [NT store]; s2 = rowsum(h1).
__global__ __launch_bounds__(256) void k3_layer1(
    const float* __restrict__ x, const float* __restrict__ W1,
    const float* __restrict__ b1, const unsigned* __restrict__ pcomb,
    float* __restrict__ h1, float* __restrict__ s2, float* __restrict__ degf) {
    __shared__ float W1s[NODE_DIM * HIDDEN];   // 32 KB
    __shared__ float xs[32 * NODE_DIM];        // 8 KB
    __shared__ float mean1s[32];
    __shared__ int redc[4][32], reds[4][32];
    int tid  = threadIdx.x;
    int base = blockIdx.x * 32;
    {   // coalesced: r = tid&31 (consecutive addresses across lanes), jg = tid>>5
        int r = tid & 31, jg = tid >> 5;      // jg 0..7
        int c = 0, sq = 0;
        #pragma unroll
        for (int k = 0; k < 16; ++k) {
            unsigned v = pcomb[(size_t)(jg * 16 + k) * N_TOTAL + base + r];
            int n_i = (int)(v >> 26);
            c  += n_i;
            sq += (int)(v & 0x03FFFFFFu) - n_i * C1;
        }
        c  += __shfl_xor(c, 32);
        sq += __shfl_xor(sq, 32);
        int w = tid >> 6, l = tid & 63;
        if (l < 32) { redc[w][l] = c; reds[w][l] = sq; }
    }
    {
        const float4* Wv = (const float4*)W1;
        float4* Wsv = (float4*)W1s;
        for (int i = tid; i < NODE_DIM * HIDDEN / 4; i += 256) Wsv[i] = Wv[i];
        const float4* xv = (const float4*)(x + base * NODE_DIM);
        float4* xsv = (float4*)xs;
        for (int i = tid; i < 32 * NODE_DIM / 4; i += 256) xsv[i] = xv[i];
    }
    __syncthreads();
    if (tid < 32) {
        int C = redc[0][tid] + redc[1][tid] + redc[2][tid] + redc[3][tid];
        int S = reds[0][tid] + reds[1][tid] + reds[2][tid] + reds[3][tid];
        mean1s[tid] = C > 0 ? ((float)S * ISC1) / (float)C : 0.f;
        degf[base + tid] = (float)C;
    }
    __syncthreads();
    int lane32 = tid & 31;
    int rg     = tid >> 5;            // 0..7
    int c4     = lane32 * 4;
    int r0     = rg * 4;
    float a[4][4];
    #pragma unroll
    for (int i = 0; i < 4; ++i)
        #pragma unroll
        for (int jj = 0; jj < 4; ++jj) a[i][jj] = 0.f;
    #pragma unroll
    for (int k = 0; k < NODE_DIM; ++k) {
        float4 w = *(const float4*)&W1s[k * HIDDEN + c4];
        #pragma unroll
        for (int i = 0; i < 4; ++i) {
            float xv = xs[(r0 + i) * NODE_DIM + k];
            a[i][0] = fmaf(xv, w.x, a[i][0]);
            a[i][1] = fmaf(xv, w.y, a[i][1]);
            a[i][2] = fmaf(xv, w.z, a[i][2]);
            a[i][3] = fmaf(xv, w.w, a[i][3]);
        }
    }
    float4 bb = *(const float4*)&b1[c4];
    #pragma unroll
    for (int i = 0; i < 4; ++i) {
        int row  = r0 + i;
        int grow = base + row;
        float mean = mean1s[row];
        v4f v;
        v.x = fmaxf(mean + a[i][0] + bb.x, 0.f);
        v.y = fmaxf(mean + a[i][1] + bb.y, 0.f);
        v.z = fmaxf(mean + a[i][2] + bb.z, 0.f);
        v.w = fmaxf(mean + a[i][3] + bb.w, 0.f);
        __builtin_nontemporal_store(v, (v4f*)&h1[grow * HIDDEN + c4]);
        float rs = v.x + v.y + v.z + v.w;
        for (int off = 16; off; off >>= 1) rs += __shfl_xor(rs, off);
        if (lane32 == 0) s2[grow] = rs;
    }
}

// ---------------------------------------------------------------- K6
// 32 rows/block. Prologue: coalesced reduce of s2 partials / degf -> mean2.
// Main: left/right = relu(mean2 + h1@W2 + b2) . wlin halves.
__global__ __launch_bounds__(256) void k6_layer2(
    const float* __restrict__ h1, const float* __restrict__ W2,
    const float* __restrict__ b2, const int* __restrict__ ps2,
    const float* __restrict__ degf, const float* __restrict__ wlin,
    float* __restrict__ left, float* __restrict__ right) {
    __shared__ float W2s[64 * HIDDEN];   // 32 KB chunk
    __shared__ float hs[32 * HIDDEN];    // 16 KB
    __shared__ float mean2s[32];
    __shared__ int reds[4][32];
    int tid  = threadIdx.x;
    int base = blockIdx.x * 32;
    {
        int r = tid & 31, jg = tid >> 5;
        int sq = 0;
        #pragma unroll
        for (int k = 0; k < 16; ++k)
            sq += ps2[(size_t)(jg * 16 + k) * N_TOTAL + base + r];
        sq += __shfl_xor(sq, 32);
        int w = tid >> 6, l = tid & 63;
        if (l < 32) reds[w][l] = sq;
    }
    {
        const float4* hv = (const float4*)(h1 + base * HIDDEN);
        float4* hsv = (float4*)hs;
        for (int i = tid; i < 32 * HIDDEN / 4; i += 256) hsv[i] = hv[i];
    }
    __syncthreads();
    if (tid < 32) {
        int S = reds[0][tid] + reds[1][tid] + reds[2][tid] + reds[3][tid];
        float d = degf[base + tid];
        mean2s[tid] = d > 0.f ? ((float)S * ISC2) / d : 0.f;
    }
    int lane32 = tid & 31;
    int rg     = tid >> 5;
    int c4     = lane32 * 4;
    int r0     = rg * 4;
    float a[4][4];
    #pragma unroll
    for (int i = 0; i < 4; ++i)
        #pragma unroll
        for (int jj = 0; jj < 4; ++jj) a[i][jj] = 0.f;
    for (int chunk = 0; chunk < 2; ++chunk) {
        __syncthreads();
        {
            const float4* Wv = (const float4*)(W2 + chunk * 64 * HIDDEN);
            float4* Wsv = (float4*)W2s;
            for (int i = tid; i < 64 * HIDDEN / 4; i += 256) Wsv[i] = Wv[i];
        }
        __syncthreads();
        int kb = chunk * 64;
        #pragma unroll 8
        for (int k = 0; k < 64; ++k) {
            float4 w = *(const float4*)&W2s[k * HIDDEN + c4];
            #pragma unroll
            for (int i = 0; i < 4; ++i) {
                float hv = hs[(r0 + i) * HIDDEN + kb + k];
                a[i][0] = fmaf(hv, w.x, a[i][0]);
                a[i][1] = fmaf(hv, w.y, a[i][1]);
                a[i][2] = fmaf(hv, w.z, a[i][2]);
                a[i][3] = fmaf(hv, w.w, a[i][3]);
            }
        }
    }
    float4 bb  = *(const float4*)&b2[c4];
    float4 wl  = *(const float4*)&wlin[c4];
    float4 wr  = *(const float4*)&wlin[HIDDEN + c4];
    #pragma unroll
    for (int i = 0; i < 4; ++i) {
        int row  = r0 + i;
        int grow = base + row;
        float ag = mean2s[row];
        float h0e = fmaxf(ag + a[i][0] + bb.x, 0.f);
        float h1e = fmaxf(ag + a[i][1] + bb.y, 0.f);
        float h2e = fmaxf(ag + a[i][2] + bb.z, 0.f);
        float h3e = fmaxf(ag + a[i][3] + bb.w, 0.f);
        float lp = h0e * wl.x + h1e * wl.y + h2e * wl.z + h3e * wl.w;
        float rp = h0e * wr.x + h1e * wr.y + h2e * wr.z + h3e * wr.w;
        for (int off = 16; off; off >>= 1) {
            lp += __shfl_xor(lp, off);
            rp += __shfl_xor(rp, off);
        }
        if (lane32 == 0) { left[grow] = lp; right[grow] = rp; }
    }
}

// ---------------------------------------------------------------- K7
// 16 rows per block; right row L1-resident; nontemporal v4f stores.
__global__ __launch_bounds__(256) void k7_scores(
    const float* __restrict__ left, const float* __restrict__ right,
    const float* __restrict__ blin, float* __restrict__ out) {
    int tid  = threadIdx.x;
    int base = blockIdx.x * 16;
    float bl = blin[0];
    const v4f* rv4 = (const v4f*)(right + ((base >> 11) << 11));
    #pragma unroll 4
    for (int rr = 0; rr < 16; ++rr) {
        int r = base + rr;
        float L = left[r] + bl;
        v4f* orow = (v4f*)out + ((size_t)r << 9);
        #pragma unroll
        for (int c = tid; c < 512; c += 256) {
            v4f rv = rv4[c];
            v4f o;
            o.x = 1.f / (1.f + __expf(-(L + rv.x)));
            o.y = 1.f / (1.f + __expf(-(L + rv.y)));
            o.z = 1.f / (1.f + __expf(-(L + rv.z)));
            o.w = 1.f / (1.f + __expf(-(L + rv.w)));
            __builtin_nontemporal_store(o, orow + c);
        }
    }
}

// ---------------------------------------------------------------- launch
extern "C" void kernel_launch(void* const* d_in, const int* in_sizes, int n_in,
                              void* d_out, int out_size, void* d_ws, size_t ws_size,
                              hipStream_t stream) {
    const float* x    = (const float*)d_in[0];
    const void*  ei   = d_in[1];
    const float* W1   = (const float*)d_in[2];
    const float* b1   = (const float*)d_in[3];
    const float* W2   = (const float*)d_in[4];
    const float* b2   = (const float*)d_in[5];
    const float* wlin = (const float*)d_in[6];
    const float* blin = (const float*)d_in[7];
    int E = in_sizes[1] / 2;

    float* ws    = (float*)d_ws;
    float* s1    = ws;                                     // N
    float* s2    = ws + 1 * N_TOTAL;
    float* degf  = ws + 2 * N_TOTAL;
    float* left  = ws + 3 * N_TOTAL;
    float* right = ws + 4 * N_TOTAL;
    float* h1    = ws + 5 * N_TOTAL;                       // N * 128
    unsigned* dec = (unsigned*)(h1 + (size_t)HIDDEN * N_TOTAL);  // E u32
    float* out   = (float*)d_out;

    // Partials live in d_out's head (16 MB << 127 MB); fully consumed by
    // k3/k6 before k7 overwrites the whole buffer (stream order).
    unsigned* pcomb = (unsigned*)d_out;                    // NPART * N u32
    int*      ps2   = (int*)d_out + (size_t)NPART * N_TOTAL;

    kS1<<<N_TOTAL / 16, 256, 0, stream>>>(x, s1);
    kScat1<<<NPART, 512, 0, stream>>>(ei, E, s1, pcomb, dec);
    k3_layer1<<<N_TOTAL / 32, 256, 0, stream>>>(x, W1, b1, pcomb, h1, s2, degf);
    kScat2<<<NPART, 512, 0, stream>>>(dec, E, s2, ps2);
    k6_layer2<<<N_TOTAL / 32, 256, 0, stream>>>(h1, W2, b2, ps2, degf, wlin, left, right);
    k7_scores<<<N_TOTAL / 16, 256, 0, stream>>>(left, right, blin, out);
}